// Round 1
// baseline (423.828 us; speedup 1.0000x reference)
//
#include <hip/hip_runtime.h>

#define D 256
#define R 32
#define ROWS 8
#define BLOCK 256

// eff_dt = DT * DT_SCALE = 0.01 ; h = 0.5*eff_dt ; mu = 0 -> 1/(1+h*mu) = 1
constexpr float EFF_DT = 0.01f;
constexpr float HH     = 0.005f;

__global__ __launch_bounds__(BLOCK, 2) void leapfrog_fp32(
    const float* __restrict__ x_in, const float* __restrict__ v_in,
    const float* __restrict__ f_in, const float* __restrict__ Ug,
    const float* __restrict__ Wg, const int* __restrict__ steps_p,
    float* __restrict__ out)
{
    // U transposed: Ut[r][d], padded stride 260 (1040 B, 16B-aligned, bank-shift 4/row)
    __shared__ float Ut[R][D + 4];
    __shared__ float Wsh[R * D];          // W[r][d] natural layout
    __shared__ float vb[ROWS][D + 4];     // v rows, padded stride 260
    __shared__ float t2s[ROWS][R];

    const int tid  = threadIdx.x;
    const int row0 = blockIdx.x * ROWS;

    // ---- stage U (transposed) and W into LDS ----
    for (int i = tid; i < D * R; i += BLOCK) {
        int d = i >> 5, r = i & 31;       // Ug is [D][R] row-major
        Ut[r][d] = Ug[i];
    }
    {
        const float4* w4 = (const float4*)Wg;
        float4* ws4 = (float4*)Wsh;
        for (int i = tid; i < D * R / 4; i += BLOCK) ws4[i] = w4[i];
    }

    // ---- per-thread elementwise ownership: row = tid>>5, two float4 chunks ----
    const int erow = tid >> 5;
    const int dA   = (tid & 31) * 4;
    const int dB   = dA + 128;
    const int gbase = (row0 + erow) * D;

    float x[8], f[8];
    {
        float4 xa = *(const float4*)&x_in[gbase + dA];
        float4 xb = *(const float4*)&x_in[gbase + dB];
        float4 fa = *(const float4*)&f_in[gbase + dA];
        float4 fb = *(const float4*)&f_in[gbase + dB];
        x[0]=xa.x; x[1]=xa.y; x[2]=xa.z; x[3]=xa.w;
        x[4]=xb.x; x[5]=xb.y; x[6]=xb.z; x[7]=xb.w;
        f[0]=fa.x; f[1]=fa.y; f[2]=fa.z; f[3]=fa.w;
        f[4]=fb.x; f[5]=fb.y; f[6]=fb.z; f[7]=fb.w;
        float4 va = *(const float4*)&v_in[gbase + dA];
        float4 vv = *(const float4*)&v_in[gbase + dB];
        *(float4*)&vb[erow][dA] = va;
        *(float4*)&vb[erow][dB] = vv;
    }
    __syncthreads();

    const int nsteps = *steps_p;

    // phase-A mapping: row = tid>>5, r = tid&31
    const int arow = tid >> 5;
    const int ar   = tid & 31;

    for (int s = 0; s < nsteps; ++s) {
        #pragma unroll
        for (int half = 0; half < 2; ++half) {
            // ---------- phase A: t2s[row][r] = (sum_d v[row][d]*U[d][r])^2 ----------
            {
                float a0 = 0.f, a1 = 0.f, a2 = 0.f, a3 = 0.f;
                #pragma unroll
                for (int d = 0; d < D; d += 8) {
                    float4 va = *(const float4*)&vb[arow][d];
                    float4 v2 = *(const float4*)&vb[arow][d + 4];
                    float4 ua = *(const float4*)&Ut[ar][d];
                    float4 ub = *(const float4*)&Ut[ar][d + 4];
                    a0 = fmaf(va.x, ua.x, a0);
                    a1 = fmaf(va.y, ua.y, a1);
                    a2 = fmaf(va.z, ua.z, a2);
                    a3 = fmaf(va.w, ua.w, a3);
                    a0 = fmaf(v2.x, ub.x, a0);
                    a1 = fmaf(v2.y, ub.y, a1);
                    a2 = fmaf(v2.z, ub.z, a2);
                    a3 = fmaf(v2.w, ub.w, a3);
                }
                float t = (a0 + a1) + (a2 + a3);
                t2s[arow][ar] = t * t;
            }
            __syncthreads();

            // ---------- phase B: gamma = t2 @ W ; v += h*(f - gamma) ; x += dt*v ----------
            {
                float acc[8];
                #pragma unroll
                for (int j = 0; j < 8; ++j) acc[j] = 0.f;
                #pragma unroll
                for (int r = 0; r < R; ++r) {
                    float t0 = t2s[erow][r];
                    float4 wa = *(const float4*)&Wsh[r * D + dA];
                    float4 wbv = *(const float4*)&Wsh[r * D + dB];
                    acc[0] = fmaf(t0, wa.x,  acc[0]);
                    acc[1] = fmaf(t0, wa.y,  acc[1]);
                    acc[2] = fmaf(t0, wa.z,  acc[2]);
                    acc[3] = fmaf(t0, wa.w,  acc[3]);
                    acc[4] = fmaf(t0, wbv.x, acc[4]);
                    acc[5] = fmaf(t0, wbv.y, acc[5]);
                    acc[6] = fmaf(t0, wbv.z, acc[6]);
                    acc[7] = fmaf(t0, wbv.w, acc[7]);
                }
                float4 va = *(const float4*)&vb[erow][dA];
                float4 v2 = *(const float4*)&vb[erow][dB];
                float vn[8];
                vn[0]=va.x; vn[1]=va.y; vn[2]=va.z; vn[3]=va.w;
                vn[4]=v2.x; vn[5]=v2.y; vn[6]=v2.z; vn[7]=v2.w;
                #pragma unroll
                for (int j = 0; j < 8; ++j) {
                    vn[j] = fmaf(HH, f[j] - acc[j], vn[j]);
                    if (half == 0) x[j] = fmaf(EFF_DT, vn[j], x[j]);
                }
                float4 oa = make_float4(vn[0], vn[1], vn[2], vn[3]);
                float4 ob = make_float4(vn[4], vn[5], vn[6], vn[7]);
                *(float4*)&vb[erow][dA] = oa;
                *(float4*)&vb[erow][dB] = ob;
            }
            __syncthreads();
        }
    }

    // ---- write out: [cx (B*D) | cv (B*D)] ----
    {
        float4 xa = make_float4(x[0], x[1], x[2], x[3]);
        float4 xb = make_float4(x[4], x[5], x[6], x[7]);
        *(float4*)&out[gbase + dA] = xa;
        *(float4*)&out[gbase + dB] = xb;
        const int B_D = 32768 * D;
        float4 va = *(const float4*)&vb[erow][dA];
        float4 v2 = *(const float4*)&vb[erow][dB];
        *(float4*)&out[B_D + gbase + dA] = va;
        *(float4*)&out[B_D + gbase + dB] = v2;
    }
}

extern "C" void kernel_launch(void* const* d_in, const int* in_sizes, int n_in,
                              void* d_out, int out_size, void* d_ws, size_t ws_size,
                              hipStream_t stream) {
    (void)in_sizes; (void)n_in; (void)d_ws; (void)ws_size; (void)out_size;
    const float* x_in = (const float*)d_in[0];
    const float* v_in = (const float*)d_in[1];
    const float* f_in = (const float*)d_in[2];
    const float* Ug   = (const float*)d_in[3];
    const float* Wg   = (const float*)d_in[4];
    const int*   st   = (const int*)d_in[5];
    float* out = (float*)d_out;

    dim3 grid(32768 / ROWS), block(BLOCK);
    hipLaunchKernelGGL(leapfrog_fp32, grid, block, 0, stream,
                       x_in, v_in, f_in, Ug, Wg, st, out);
}

// Round 2
// 71.052 us; speedup vs baseline: 5.9650x; 5.9650x over previous
//
#include <hip/hip_runtime.h>
#include <stddef.h>

typedef __attribute__((ext_vector_type(4))) float  f32x4;
typedef __attribute__((ext_vector_type(8))) short  bf16x8;
typedef __attribute__((ext_vector_type(4))) short  bf16x4;

constexpr float EFF_DT = 0.01f;   // DT * DT_SCALE
constexpr float HH     = 0.005f;  // 0.5 * eff_dt ; mu = 0

__device__ inline short f2bf(float x) {
    union { float f; unsigned u; } c; c.f = x;
    unsigned r = c.u + 0x7FFFu + ((c.u >> 16) & 1u);   // RNE
    return (short)(r >> 16);
}

// Block: 256 threads = 4 waves, 32 batch rows.
// LDS map:
//   [0, 32KB)      x_l  : fp32, lane-linear per (wave,tile)   (init: aliases U/W bf16 staging)
//   [32KB, 48KB)   vbf  : bf16 [2 rt][16 dblk][16 d'][16 row]
//   [48KB, 50KB)   t2l  : bf16 [2 rt][2 rblk][16 r'][16 row]
__global__ __launch_bounds__(256, 2) void leapfrog_mfma(
    const float* __restrict__ x_in, const float* __restrict__ v_in,
    const float* __restrict__ f_in, const float* __restrict__ Ug,
    const float* __restrict__ Wg, const int* __restrict__ steps_p,
    float* __restrict__ out)
{
    __shared__ __align__(16) char lds[51200];
    float* x_l = (float*)lds;
    short* vbf = (short*)(lds + 32768);
    short* t2l = (short*)(lds + 32768 + 16384);

    const int tid  = threadIdx.x;
    const int w    = tid >> 6;
    const int lane = tid & 63;
    const int g    = lane >> 4;       // k-group (0..3)
    const int c16  = lane & 15;       // tile column (C layout) / A-row (A layout)
    const int row0 = blockIdx.x * 32;

    const int a_rt = w >> 1, a_rr = w & 1;   // phase A: (rowtile, r-tile)
    const int b_rt = w >> 1, b_dh = w & 1;   // phase B: (rowtile, d-half)

    // ---- stage U, W as bf16 into the x_l region (coalesced float4) ----
    {
        const f32x4* U4 = (const f32x4*)Ug;   // 2048 float4 (U: [256][32])
        const f32x4* W4 = (const f32x4*)Wg;   // 2048 float4 (W: [32][256])
        bf16x4* ub = (bf16x4*)lds;
        bf16x4* wb = (bf16x4*)(lds + 16384);
        for (int i = tid; i < 2048; i += 256) {
            f32x4 u = U4[i];
            bf16x4 pu; pu[0]=f2bf(u[0]); pu[1]=f2bf(u[1]); pu[2]=f2bf(u[2]); pu[3]=f2bf(u[3]);
            ub[i] = pu;
            f32x4 ww = W4[i];
            bf16x4 pw; pw[0]=f2bf(ww[0]); pw[1]=f2bf(ww[1]); pw[2]=f2bf(ww[2]); pw[3]=f2bf(ww[3]);
            wb[i] = pw;
        }
    }
    __syncthreads();

    // ---- build static B-fragments with the tr-read-matching k-map:
    //      slot j  ->  k = (j>>2)*16 + g*4 + (j&3)   (per 32-k chunk)
    bf16x8 ufrag[8], wfrag[8];
    {
        const short* Ubf = (const short*)lds;            // [256 d][32 r]
        const short* Wbf = (const short*)(lds + 16384);  // [32 r][256 d]
        #pragma unroll
        for (int c = 0; c < 8; ++c) {
            #pragma unroll
            for (int j = 0; j < 8; ++j) {
                int k = c*32 + ((j>>2)<<4) + g*4 + (j&3);
                ufrag[c][j] = Ubf[k*32 + a_rr*16 + c16];
            }
        }
        #pragma unroll
        for (int t = 0; t < 8; ++t) {
            #pragma unroll
            for (int j = 0; j < 8; ++j) {
                int r = ((j>>2)<<4) + g*4 + (j&3);
                wfrag[t][j] = Wbf[r*256 + (b_dh*8 + t)*16 + c16];
            }
        }
    }
    __syncthreads();   // frags built; x_l region free for x

    // ---- load x, v, f at C-fragment positions; seed vbf + x_l ----
    float vr[8][4], fr[8][4];
    const int rbase = row0 + b_rt*16 + g*4;
    #pragma unroll
    for (int t = 0; t < 8; ++t) {
        const int d = (b_dh*8 + t)*16 + c16;
        f32x4 xv;
        bf16x4 pv;
        #pragma unroll
        for (int j = 0; j < 4; ++j) {
            const int gi = (rbase + j)*256 + d;
            vr[t][j] = v_in[gi];
            fr[t][j] = f_in[gi];
            xv[j]    = x_in[gi];
            pv[j]    = f2bf(vr[t][j]);
        }
        *(f32x4*)&x_l[(w*8 + t)*256 + lane*4] = xv;
        *(bf16x4*)&vbf[b_rt*4096 + (b_dh*8 + t)*256 + c16*16 + g*4] = pv;
    }
    __syncthreads();

    const int nsteps = *steps_p;
    const unsigned vbf_base = (unsigned)(size_t)vbf;
    const unsigned t2_base  = (unsigned)(size_t)t2l;
    const unsigned laneoff  = (unsigned)(lane * 8);

    for (int s = 0; s < nsteps; ++s) {
        #pragma unroll
        for (int half = 0; half < 2; ++half) {
            // ================= phase A : T = V @ U (one 16x16 tile/wave) ==========
            f32x4 acc0 = {0.f,0.f,0.f,0.f}, acc1 = {0.f,0.f,0.f,0.f};
            #pragma unroll
            for (int cc = 0; cc < 2; ++cc) {
                bf16x4 p[8];
                const unsigned a0 = vbf_base + (unsigned)(a_rt*8192 + cc*4096) + laneoff;
                #pragma unroll
                for (int q = 0; q < 4; ++q) {
                    asm volatile("ds_read_b64_tr_b16 %0, %2 offset:0\n\t"
                                 "ds_read_b64_tr_b16 %1, %2 offset:512"
                                 : "=v"(p[2*q]), "=v"(p[2*q+1])
                                 : "v"(a0 + (unsigned)(q*1024)));
                }
                asm volatile("s_waitcnt lgkmcnt(0)" ::: "memory");
                __builtin_amdgcn_sched_barrier(0);
                #pragma unroll
                for (int q = 0; q < 4; ++q) {
                    bf16x8 af;
                    af[0]=p[2*q][0]; af[1]=p[2*q][1]; af[2]=p[2*q][2]; af[3]=p[2*q][3];
                    af[4]=p[2*q+1][0]; af[5]=p[2*q+1][1]; af[6]=p[2*q+1][2]; af[7]=p[2*q+1][3];
                    if (q & 1) acc1 = __builtin_amdgcn_mfma_f32_16x16x32_bf16(af, ufrag[cc*4+q], acc1, 0, 0, 0);
                    else       acc0 = __builtin_amdgcn_mfma_f32_16x16x32_bf16(af, ufrag[cc*4+q], acc0, 0, 0, 0);
                }
            }
            {
                bf16x4 pt;
                #pragma unroll
                for (int j = 0; j < 4; ++j) {
                    float tt = acc0[j] + acc1[j];
                    tt *= tt;
                    pt[j] = f2bf(tt);
                }
                *(bf16x4*)&t2l[a_rt*512 + a_rr*256 + c16*16 + g*4] = pt;
            }
            __syncthreads();

            // ================= phase B : Gamma = T2 @ W ; update v, x =============
            bf16x4 q0, q1;
            {
                const unsigned tb = t2_base + (unsigned)(b_rt*1024) + laneoff;
                asm volatile("ds_read_b64_tr_b16 %0, %2 offset:0\n\t"
                             "ds_read_b64_tr_b16 %1, %2 offset:512"
                             : "=v"(q0), "=v"(q1) : "v"(tb));
                asm volatile("s_waitcnt lgkmcnt(0)" ::: "memory");
                __builtin_amdgcn_sched_barrier(0);
            }
            bf16x8 t2f;
            t2f[0]=q0[0]; t2f[1]=q0[1]; t2f[2]=q0[2]; t2f[3]=q0[3];
            t2f[4]=q1[0]; t2f[5]=q1[1]; t2f[6]=q1[2]; t2f[7]=q1[3];

            f32x4 gacc[8];
            #pragma unroll
            for (int t = 0; t < 8; ++t) {
                f32x4 z = {0.f,0.f,0.f,0.f};
                gacc[t] = __builtin_amdgcn_mfma_f32_16x16x32_bf16(t2f, wfrag[t], z, 0, 0, 0);
            }
            #pragma unroll
            for (int t = 0; t < 8; ++t) {
                bf16x4 pv;
                #pragma unroll
                for (int j = 0; j < 4; ++j) {
                    vr[t][j] = fmaf(HH, fr[t][j] - gacc[t][j], vr[t][j]);
                    pv[j] = f2bf(vr[t][j]);
                }
                *(bf16x4*)&vbf[b_rt*4096 + (b_dh*8 + t)*256 + c16*16 + g*4] = pv;
                if (half == 0) {
                    f32x4 xv = *(f32x4*)&x_l[(w*8 + t)*256 + lane*4];
                    #pragma unroll
                    for (int j = 0; j < 4; ++j) xv[j] = fmaf(EFF_DT, vr[t][j], xv[j]);
                    *(f32x4*)&x_l[(w*8 + t)*256 + lane*4] = xv;
                }
            }
            __syncthreads();
        }
    }

    // ---- epilogue: out = [cx | cv] ----
    const int BD = 32768 * 256;
    #pragma unroll
    for (int t = 0; t < 8; ++t) {
        const int d = (b_dh*8 + t)*16 + c16;
        f32x4 xv = *(f32x4*)&x_l[(w*8 + t)*256 + lane*4];
        #pragma unroll
        for (int j = 0; j < 4; ++j) {
            const int gi = (rbase + j)*256 + d;
            out[gi]      = xv[j];
            out[BD + gi] = vr[t][j];
        }
    }
}

extern "C" void kernel_launch(void* const* d_in, const int* in_sizes, int n_in,
                              void* d_out, int out_size, void* d_ws, size_t ws_size,
                              hipStream_t stream) {
    (void)in_sizes; (void)n_in; (void)d_ws; (void)ws_size; (void)out_size;
    const float* x_in = (const float*)d_in[0];
    const float* v_in = (const float*)d_in[1];
    const float* f_in = (const float*)d_in[2];
    const float* Ug   = (const float*)d_in[3];
    const float* Wg   = (const float*)d_in[4];
    const int*   st   = (const int*)d_in[5];
    float* out = (float*)d_out;

    dim3 grid(32768 / 32), block(256);
    hipLaunchKernelGGL(leapfrog_mfma, grid, block, 0, stream,
                       x_in, v_in, f_in, Ug, Wg, st, out);
}

// Round 3
// 59.729 us; speedup vs baseline: 7.0958x; 1.1896x over previous
//
#include <hip/hip_runtime.h>

typedef __attribute__((ext_vector_type(4))) float f32x4;
typedef __attribute__((ext_vector_type(8))) short bf16x8;
typedef __attribute__((ext_vector_type(4))) short bf16x4;

constexpr float EFF_DT = 0.01f;   // DT * DT_SCALE
constexpr float HH     = 0.005f;  // 0.5 * eff_dt ; mu = 0

__device__ inline short f2bf(float x){
    union{float f;unsigned u;}c; c.f=x;
    unsigned r=c.u+0x7FFFu+((c.u>>16)&1u);
    return (short)(r>>16);
}
__device__ inline unsigned cvtpk(float lo,float hi){
    unsigned r; asm("v_cvt_pk_bf16_f32 %0, %1, %2":"=v"(r):"v"(lo),"v"(hi)); return r;
}
__device__ inline float ubflo(unsigned u){union{unsigned x;float f;}c;c.x=u<<16;return c.f;}
__device__ inline float ubfhi(unsigned u){union{unsigned x;float f;}c;c.x=u&0xffff0000u;return c.f;}

union VP4 { unsigned u[4]; bf16x8 h; };

// Block = 256 threads (4 waves); each wave owns 16 batch rows, barrier-free main loop.
// Lane (g=lane>>4, c=lane&15): holds, for all 16 d-tiles, elements
//   d = dt*16 + g*4 + j (j=0..3) of batch row (R0+c)  — the C-layout of the
//   swapped-operand MFMAs, which is ALSO the A/B fragment k-slot layout.
// LDS: [0,16K) W A-frags lane-major; [16K,32K)/[32K,48K) U/W bf16 staging (transient);
//      [16K,80K) per-wave xacc fp32 (after staging is consumed).
__global__ __launch_bounds__(256,2) void leapfrog_reg(
    const float* __restrict__ x_in, const float* __restrict__ v_in,
    const float* __restrict__ f_in, const float* __restrict__ Ug,
    const float* __restrict__ Wg, const int* __restrict__ steps_p,
    float* __restrict__ out)
{
    __shared__ __align__(16) char lds[81920];
    short* WF  = (short*)lds;             // [16 dt][64 lane][8 shorts]
    short* Ubf = (short*)(lds + 16384);   // staging, [256 d][32 r]
    short* Wbf = (short*)(lds + 32768);   // staging, [32 r][256 d]

    const int tid = threadIdx.x, w = tid>>6, lane = tid&63, g = lane>>4, c = lane&15;
    const int R0  = blockIdx.x*64 + w*16;
    float* xacc = (float*)(lds + 16384 + w*16384);   // [16 dt][64 lane][4] fp32

    // ---- stage U, W as bf16 (coalesced) ----
    {
        const f32x4* U4=(const f32x4*)Ug; const f32x4* W4=(const f32x4*)Wg;
        bf16x4* ub=(bf16x4*)Ubf; bf16x4* wb=(bf16x4*)Wbf;
        for(int i=tid;i<2048;i+=256){
            f32x4 u=U4[i]; bf16x4 pu;
            pu[0]=f2bf(u[0]);pu[1]=f2bf(u[1]);pu[2]=f2bf(u[2]);pu[3]=f2bf(u[3]); ub[i]=pu;
            f32x4 ww=W4[i]; bf16x4 pw;
            pw[0]=f2bf(ww[0]);pw[1]=f2bf(ww[1]);pw[2]=f2bf(ww[2]);pw[3]=f2bf(ww[3]); wb[i]=pw;
        }
    }
    __syncthreads();

    // ---- A-frags of U^T (regs): uf[rt][cc], row = rt*16+c, k(=d) = cc*32+kmap(g,j) ----
    bf16x8 uf[2][8];
    #pragma unroll
    for(int rt=0;rt<2;++rt)
        #pragma unroll
        for(int cc=0;cc<8;++cc)
            #pragma unroll
            for(int j=0;j<8;++j){
                int d = cc*32 + ((j>>2)<<4) + g*4 + (j&3);
                uf[rt][cc][j] = Ubf[d*32 + rt*16 + c];
            }
    // ---- A-frags of W^T (LDS lane-major): WF[dt][lane], row = dt*16+c, k(=r)=kmap(g,j) ----
    #pragma unroll
    for(int i=0;i<4;++i){
        int dt = w*4 + i;
        #pragma unroll
        for(int j=0;j<8;++j){
            int r = ((j>>2)<<4) + g*4 + (j&3);
            WF[dt*512 + lane*8 + j] = Wbf[r*256 + dt*16 + c];
        }
    }
    __syncthreads();   // staging regions now free -> xacc

    // ---- load v, f, x ; init packed state ----
    f32x4 vv[16];
    unsigned fpk[16][2];
    VP4 vp[8];
    const int gb = (R0 + c)*256 + g*4;
    #pragma unroll
    for(int dt=0;dt<16;++dt){
        vv[dt] = *(const f32x4*)&v_in[gb + dt*16];
        f32x4 ff = *(const f32x4*)&f_in[gb + dt*16];
        fpk[dt][0] = cvtpk(HH*ff[0], HH*ff[1]);
        fpk[dt][1] = cvtpk(HH*ff[2], HH*ff[3]);
        f32x4 xx = *(const f32x4*)&x_in[gb + dt*16];
        f32x4 xs; xs[0]=xx[0]*100.f; xs[1]=xx[1]*100.f; xs[2]=xx[2]*100.f; xs[3]=xx[3]*100.f;
        *(f32x4*)&xacc[dt*256 + lane*4] = xs;   // xacc = x0/eff_dt
    }
    #pragma unroll
    for(int cc=0;cc<8;++cc){
        vp[cc].u[0]=cvtpk(vv[2*cc][0],  vv[2*cc][1]);
        vp[cc].u[1]=cvtpk(vv[2*cc][2],  vv[2*cc][3]);
        vp[cc].u[2]=cvtpk(vv[2*cc+1][0],vv[2*cc+1][1]);
        vp[cc].u[3]=cvtpk(vv[2*cc+1][2],vv[2*cc+1][3]);
    }

    const int nsteps = *steps_p;
    const f32x4 zero = {0.f,0.f,0.f,0.f};

    for(int s=0;s<nsteps;++s){
        #pragma unroll
        for(int half=0;half<2;++half){
            // ===== phase A: T^T = U^T @ V^T  (2 r-tiles, K=256) =====
            f32x4 t0=zero, t1=zero;
            #pragma unroll
            for(int cc=0;cc<8;++cc){
                t0=__builtin_amdgcn_mfma_f32_16x16x32_bf16(uf[0][cc], vp[cc].h, t0, 0,0,0);
                t1=__builtin_amdgcn_mfma_f32_16x16x32_bf16(uf[1][cc], vp[cc].h, t1, 0,0,0);
            }
            VP4 t2;
            t2.u[0]=cvtpk(t0[0]*t0[0], t0[1]*t0[1]);
            t2.u[1]=cvtpk(t0[2]*t0[2], t0[3]*t0[3]);
            t2.u[2]=cvtpk(t1[0]*t1[0], t1[1]*t1[1]);
            t2.u[3]=cvtpk(t1[2]*t1[2], t1[3]*t1[3]);

            // ===== phase B: Gamma^T = W^T @ T2^T ; update v (and xacc at half 0) =====
            #pragma unroll
            for(int dt=0;dt<16;++dt){
                bf16x8 wf = *(bf16x8*)&WF[dt*512 + lane*8];
                f32x4 gm = __builtin_amdgcn_mfma_f32_16x16x32_bf16(wf, t2.h, zero, 0,0,0);
                unsigned u0=fpk[dt][0], u1=fpk[dt][1];
                f32x4 nv = vv[dt];
                nv[0]=fmaf(-HH, gm[0], nv[0]+ubflo(u0));
                nv[1]=fmaf(-HH, gm[1], nv[1]+ubfhi(u0));
                nv[2]=fmaf(-HH, gm[2], nv[2]+ubflo(u1));
                nv[3]=fmaf(-HH, gm[3], nv[3]+ubfhi(u1));
                vv[dt]=nv;
                vp[dt>>1].u[2*(dt&1)+0]=cvtpk(nv[0],nv[1]);
                vp[dt>>1].u[2*(dt&1)+1]=cvtpk(nv[2],nv[3]);
                if(half==0){
                    f32x4* xs=(f32x4*)&xacc[dt*256 + lane*4];
                    f32x4 xv=*xs;
                    xv[0]+=nv[0]; xv[1]+=nv[1]; xv[2]+=nv[2]; xv[3]+=nv[3];
                    *xs=xv;
                }
            }
        }
    }

    // ---- epilogue: out = [cx | cv], cx = eff_dt * xacc ----
    const int BD = 32768*256;
    #pragma unroll
    for(int dt=0;dt<16;++dt){
        f32x4 xv=*(f32x4*)&xacc[dt*256 + lane*4];
        f32x4 xo; xo[0]=EFF_DT*xv[0]; xo[1]=EFF_DT*xv[1]; xo[2]=EFF_DT*xv[2]; xo[3]=EFF_DT*xv[3];
        *(f32x4*)&out[gb + dt*16]      = xo;
        *(f32x4*)&out[BD + gb + dt*16] = vv[dt];
    }
}

extern "C" void kernel_launch(void* const* d_in, const int* in_sizes, int n_in,
                              void* d_out, int out_size, void* d_ws, size_t ws_size,
                              hipStream_t stream) {
    (void)in_sizes; (void)n_in; (void)d_ws; (void)ws_size; (void)out_size;
    const float* x_in = (const float*)d_in[0];
    const float* v_in = (const float*)d_in[1];
    const float* f_in = (const float*)d_in[2];
    const float* Ug   = (const float*)d_in[3];
    const float* Wg   = (const float*)d_in[4];
    const int*   st   = (const int*)d_in[5];
    float* out = (float*)d_out;

    dim3 grid(32768/64), block(256);
    hipLaunchKernelGGL(leapfrog_reg, grid, block, 0, stream,
                       x_in, v_in, f_in, Ug, Wg, st, out);
}